// Round 1
// baseline (2083.058 us; speedup 1.0000x reference)
//
#include <hip/hip_runtime.h>
#include <hip/hip_bf16.h>
#include <math.h>

// Problem constants
static constexpr int cH = 512, cE = 512, cV = 32000;
static constexpr int K_SEG = 6, SOPI = 2, EOPI = 3;
static constexpr int cS = 40, cT = 40, cB = 16, cNP = 39;  // NP = T-1

// ---------------------------------------------------------------------------
// Row gather: out[r][:] = emb[idx[r]][:]  (row 640 = SOP row when extraSOP)
__global__ void k_gather(const float* __restrict__ emb, const int* __restrict__ idx,
                         float* __restrict__ out, int R, int extraSOP) {
  int r = blockIdx.x;
  if (r >= R) return;
  int tok = (extraSOP && r == R - 1) ? SOPI : idx[r];
  const float* s = emb + (size_t)tok * cE;
  float* d = out + (size_t)r * cE;
  for (int e = threadIdx.x; e < cE; e += blockDim.x) d[e] = s[e];
}

// ---------------------------------------------------------------------------
// Generic f32 GEMM: C[M,N] = A[M,K] @ B[K,N] (+bias). Output f32 or bf16.
// N multiple of 64, K multiple of 16. M guarded.
__global__ __launch_bounds__(256) void k_gemm(
    const float* __restrict__ A, const float* __restrict__ B,
    const float* __restrict__ bias, float* __restrict__ Cf,
    __hip_bfloat16* __restrict__ Cb, int M, int N, int K) {
  __shared__ float As[16][68];  // [k][m], stride 68 floats = 272 B (16B-aligned rows)
  __shared__ float Bs[16][68];  // [k][n]
  int tid = threadIdx.x;
  int m0 = blockIdx.y * 64, n0 = blockIdx.x * 64;
  int ty = tid >> 4, tx = tid & 15;
  float acc[4][4] = {};
  for (int k0 = 0; k0 < K; k0 += 16) {
    {
      int lk = tid & 15, lm = tid >> 4;
#pragma unroll
      for (int i = 0; i < 4; ++i) {
        int m = lm + i * 16;
        int gm = m0 + m;
        As[lk][m] = (gm < M) ? A[(size_t)gm * K + k0 + lk] : 0.f;
      }
      int ln = tid & 63, lk0 = tid >> 6;
#pragma unroll
      for (int i = 0; i < 4; ++i) {
        int k = lk0 + i * 4;
        Bs[k][ln] = B[(size_t)(k0 + k) * N + n0 + ln];
      }
    }
    __syncthreads();
#pragma unroll
    for (int kk = 0; kk < 16; ++kk) {
      float a[4], b[4];
#pragma unroll
      for (int i = 0; i < 4; ++i) a[i] = As[kk][ty * 4 + i];
#pragma unroll
      for (int j = 0; j < 4; ++j) b[j] = Bs[kk][tx * 4 + j];
#pragma unroll
      for (int i = 0; i < 4; ++i)
#pragma unroll
        for (int j = 0; j < 4; ++j) acc[i][j] += a[i] * b[j];
    }
    __syncthreads();
  }
#pragma unroll
  for (int i = 0; i < 4; ++i) {
    int gm = m0 + ty * 4 + i;
    if (gm >= M) continue;
#pragma unroll
    for (int j = 0; j < 4; ++j) {
      int gn = n0 + tx * 4 + j;
      float v = acc[i][j];
      if (bias) v += bias[gn];
      if (Cb) Cb[(size_t)gm * N + gn] = __float2bfloat16(v);
      else Cf[(size_t)gm * N + gn] = v;
    }
  }
}

// ---------------------------------------------------------------------------
// One GRU time step for BOTH GRUs (blockIdx.z selects). Thread per hidden unit.
__global__ __launch_bounds__(256) void k_gru_step(
    const float* __restrict__ xp0, const float* __restrict__ Wh0, float* __restrict__ hs0,
    const float* __restrict__ xp1, const float* __restrict__ Wh1, float* __restrict__ hs1,
    int t) {
  const float* xp = blockIdx.z ? xp1 : xp0;
  const float* Wh = blockIdx.z ? Wh1 : Wh0;
  float* hs = blockIdx.z ? hs1 : hs0;
  int b = blockIdx.y;
  int u = blockIdx.x * 256 + threadIdx.x;
  __shared__ float hsh[cH];
  for (int k = threadIdx.x; k < cH; k += 256)
    hsh[k] = (t == 0) ? 0.f : hs[(size_t)((t - 1) * cB + b) * cH + k];
  __syncthreads();
  int row = t * cB + b;
  const float* xr_p = xp + (size_t)row * (3 * cH);
  float xr = xr_p[u], xz = xr_p[cH + u], xn = xr_p[2 * cH + u];
  float hr = 0.f, hz = 0.f, hn = 0.f;
  for (int k = 0; k < cH; ++k) {
    float hv = hsh[k];
    const float* w = Wh + (size_t)k * (3 * cH);
    hr += hv * w[u];
    hz += hv * w[cH + u];
    hn += hv * w[2 * cH + u];
  }
  float r = 1.f / (1.f + __expf(-(xr + hr)));
  float z = 1.f / (1.f + __expf(-(xz + hz)));
  float n = tanhf(xn + r * hn);
  float h = (1.f - z) * n + z * hsh[u];
  hs[(size_t)row * cH + u] = h;
}

// ---------------------------------------------------------------------------
// energy[p,s,b] = sum_k v[k] * tanh(eproj[s,b,k] + qproj[p,b,k])
__global__ void k_energy(const float* __restrict__ eproj, const float* __restrict__ qproj,
                         const float* __restrict__ v, float* __restrict__ energy) {
  int idx = blockIdx.x * blockDim.x + threadIdx.x;
  if (idx >= cNP * cS * cB) return;
  int b = idx & (cB - 1);
  int s = (idx >> 4) % cS;
  int p = idx / (cS * cB);
  const float* ep = eproj + (size_t)(s * cB + b) * cH;
  const float* qp = qproj + (size_t)(p * cB + b) * cH;
  float acc = 0.f;
  for (int k = 0; k < cH; ++k) acc += v[k] * tanhf(ep[k] + qp[k]);
  energy[idx] = acc;
}

// softmax over s (in-place on energy -> attn). Block (p,b), 64 threads.
__global__ void k_softmax(float* __restrict__ energy) {
  int p = blockIdx.x, b = blockIdx.y;
  int s = threadIdx.x;
  float e = (s < cS) ? energy[(size_t)(p * cS + s) * cB + b] : -INFINITY;
  float m = e;
  for (int o = 32; o; o >>= 1) m = fmaxf(m, __shfl_down(m, o));
  m = __shfl(m, 0);
  float ex = (s < cS) ? __expf(e - m) : 0.f;
  float sum = ex;
  for (int o = 32; o; o >>= 1) sum += __shfl_down(sum, o);
  sum = __shfl(sum, 0);
  if (s < cS) energy[(size_t)(p * cS + s) * cB + b] = ex / sum;
}

// weighted[p,b,h] = sum_s attn[p,s,b] * enc_out[s,b,h]
__global__ void k_weighted(const float* __restrict__ attn, const float* __restrict__ enc_out,
                           float* __restrict__ weighted) {
  int h = blockIdx.x * 256 + threadIdx.x;
  int b = blockIdx.y, p = blockIdx.z;
  float acc = 0.f;
  for (int s = 0; s < cS; ++s)
    acc += attn[(size_t)(p * cS + s) * cB + b] * enc_out[(size_t)(s * cB + b) * cH + h];
  weighted[(size_t)(p * cB + b) * cH + h] = acc;
}

// ---------------------------------------------------------------------------
// logZ[p,j,b] = log sum_v exp(A[row(p,j,b),v] + C[(p,b),v]); j=0 uses SOP row 640.
__global__ __launch_bounds__(256) void k_logZ(
    const __hip_bfloat16* __restrict__ Abig, const __hip_bfloat16* __restrict__ Cbig,
    float* __restrict__ logZ) {
  int p = blockIdx.x, b = blockIdx.y;
  int tid = threadIdx.x;
  float acc[7] = {};
  const __hip_bfloat16* crow = Cbig + (size_t)(p * cB + b) * cV;
  int rows[7];
  rows[0] = cT * cB;  // SOP row (640)
#pragma unroll
  for (int j = 1; j <= 6; ++j) rows[j] = min(p + j, cT - 1) * cB + b;
  for (int v = tid; v < cV; v += 256) {
    float cv = __bfloat162float(crow[v]);
#pragma unroll
    for (int j = 0; j < 7; ++j)
      acc[j] += __expf(__bfloat162float(Abig[(size_t)rows[j] * cV + v]) + cv);
  }
  __shared__ float red[256];
#pragma unroll
  for (int j = 0; j < 7; ++j) {
    red[tid] = acc[j];
    __syncthreads();
    for (int st = 128; st; st >>= 1) {
      if (tid < st) red[tid] += red[tid + st];
      __syncthreads();
    }
    if (tid == 0) logZ[(size_t)(p * 7 + j) * cB + b] = logf(red[0]);
    __syncthreads();
  }
}

// Pm[p,j,b] = cumsum_j chain_lp + eop_lp
__global__ void k_pm(const __hip_bfloat16* __restrict__ Abig, const __hip_bfloat16* __restrict__ Cbig,
                     const float* __restrict__ logZ, const int* __restrict__ trg,
                     float* __restrict__ Pm) {
  int p = blockIdx.x;
  int b = threadIdx.x;
  if (b >= cB) return;
  const __hip_bfloat16* crow = Cbig + (size_t)(p * cB + b) * cV;
  float cEop = __bfloat162float(crow[EOPI]);
  float cum = 0.f;
  for (int j = 0; j < K_SEG; ++j) {
    int arow = (j == 0) ? (cT * cB) : (min(p + j, cT - 1) * cB + b);
    int tok = trg[min(p + 1 + j, cT - 1) * cB + b];
    float chain = __bfloat162float(Abig[(size_t)arow * cV + tok]) +
                  __bfloat162float(crow[tok]) - logZ[(size_t)(p * 7 + j) * cB + b];
    cum += chain;
    int erow = min(p + j + 1, cT - 1) * cB + b;
    float eop = __bfloat162float(Abig[(size_t)erow * cV + EOPI]) + cEop -
                logZ[(size_t)(p * 7 + j + 1) * cB + b];
    Pm[(size_t)(p * K_SEG + j) * cB + b] = cum + eop;
  }
}

// Final alpha recursion: thread b owns its row, 39 sequential steps.
__global__ void k_alpha(const float* __restrict__ Pm, float* __restrict__ out) {
  __shared__ float al[cB][cT];
  int b = threadIdx.x;
  if (b >= cB) return;
  al[b][0] = 0.f;
  for (int e = 1; e < cT; ++e) {
    float vals[K_SEG];
    float m = -INFINITY;
#pragma unroll
    for (int d = 0; d < K_SEG; ++d) {
      int p = e - 1 - d;
      float v = (p >= 0) ? al[b][p] + Pm[(size_t)(p * K_SEG + d) * cB + b] : -INFINITY;
      vals[d] = v;
      m = fmaxf(m, v);
    }
    float s = 0.f;
#pragma unroll
    for (int d = 0; d < K_SEG; ++d) s += __expf(vals[d] - m);
    al[b][e] = m + logf(s);
  }
  out[b] = al[b][cT - 1];
}

// ---------------------------------------------------------------------------
extern "C" void kernel_launch(void* const* d_in, const int* in_sizes, int n_in,
                              void* d_out, int out_size, void* d_ws, size_t ws_size,
                              hipStream_t stream) {
  const int* src = (const int*)d_in[0];
  const int* trg = (const int*)d_in[1];
  const float* emb_src = (const float*)d_in[2];
  const float* emb_trg = (const float*)d_in[3];
  const float* enc_Wx = (const float*)d_in[4];
  const float* enc_Wh = (const float*)d_in[5];
  const float* enc_b = (const float*)d_in[6];
  const float* tgt_Wx = (const float*)d_in[7];
  const float* tgt_Wh = (const float*)d_in[8];
  const float* tgt_b = (const float*)d_in[9];
  const float* attn_We = (const float*)d_in[10];
  const float* attn_Wq = (const float*)d_in[11];
  const float* attn_v = (const float*)d_in[12];
  const float* dec_W = (const float*)d_in[13];
  const float* dec_b = (const float*)d_in[14];
  float* out = (float*)d_out;

  char* ws = (char*)d_ws;
  size_t off = 0;
  auto alloc = [&](size_t bytes) -> void* {
    size_t o = (off + 255) & ~(size_t)255;
    off = o + bytes;
    return (void*)(ws + o);
  };
  float* xe_src = (float*)alloc((size_t)cS * cB * cE * 4);
  float* xe_tgt = (float*)alloc((size_t)cT * cB * cE * 4);
  float* xp_src = (float*)alloc((size_t)cS * cB * 3 * cH * 4);
  float* xp_tgt = (float*)alloc((size_t)cT * cB * 3 * cH * 4);
  float* hs_enc = (float*)alloc((size_t)cS * cB * cH * 4);
  float* hs_tgt = (float*)alloc((size_t)cT * cB * cH * 4);
  float* eproj = (float*)alloc((size_t)cS * cB * cH * 4);
  float* qproj = (float*)alloc((size_t)cNP * cB * cH * 4);
  float* energy = (float*)alloc((size_t)cNP * cS * cB * 4);
  float* weighted = (float*)alloc((size_t)cNP * cB * cH * 4);
  float* XA = (float*)alloc((size_t)(cT * cB + 1) * cE * 4);
  __hip_bfloat16* Abig = (__hip_bfloat16*)alloc((size_t)(cT * cB + 1) * cV * 2);
  __hip_bfloat16* Cbig = (__hip_bfloat16*)alloc((size_t)cNP * cB * cV * 2);
  float* logZ = (float*)alloc((size_t)cNP * 7 * cB * 4);
  float* Pm = (float*)alloc((size_t)cNP * K_SEG * cB * 4);
  if (off > ws_size) return;  // workspace too small: bail (bench will flag)

  const int MA = cT * cB + 1;  // 641 rows (incl. SOP)
  const int MC = cNP * cB;     // 624 rows

  // 1) embedding gathers
  k_gather<<<cS * cB, 256, 0, stream>>>(emb_src, src, xe_src, cS * cB, 0);
  k_gather<<<cT * cB, 256, 0, stream>>>(emb_trg, trg, xe_tgt, cT * cB, 0);
  k_gather<<<MA, 256, 0, stream>>>(emb_trg, trg, XA, MA, 1);

  // 2) xp = xe @ Wx + b
  k_gemm<<<dim3(3 * cH / 64, (cS * cB + 63) / 64), 256, 0, stream>>>(
      xe_src, enc_Wx, enc_b, xp_src, nullptr, cS * cB, 3 * cH, cE);
  k_gemm<<<dim3(3 * cH / 64, (cT * cB + 63) / 64), 256, 0, stream>>>(
      xe_tgt, tgt_Wx, tgt_b, xp_tgt, nullptr, cT * cB, 3 * cH, cE);

  // 3) GRU scans (both GRUs per launch)
  for (int t = 0; t < cT; ++t)
    k_gru_step<<<dim3(cH / 256, cB, 2), 256, 0, stream>>>(
        xp_src, enc_Wh, hs_enc, xp_tgt, tgt_Wh, hs_tgt, t);

  // 4) attention projections
  k_gemm<<<dim3(cH / 64, (cS * cB + 63) / 64), 256, 0, stream>>>(
      hs_enc, attn_We, nullptr, eproj, nullptr, cS * cB, cH, cH);
  k_gemm<<<dim3(cH / 64, (MC + 63) / 64), 256, 0, stream>>>(
      hs_tgt, attn_Wq, nullptr, qproj, nullptr, MC, cH, cH);

  // 5) energy / softmax / weighted context
  k_energy<<<(cNP * cS * cB + 255) / 256, 256, 0, stream>>>(eproj, qproj, attn_v, energy);
  k_softmax<<<dim3(cNP, cB), 64, 0, stream>>>(energy);
  k_weighted<<<dim3(cH / 256, cB, cNP), 256, 0, stream>>>(energy, hs_enc, weighted);

  // 6) decoder GEMMs -> bf16 A (token/SOP part) and C (context part + bias)
  k_gemm<<<dim3(cV / 64, (MA + 63) / 64), 256, 0, stream>>>(
      XA, dec_W, nullptr, nullptr, Abig, MA, cV, cE);
  k_gemm<<<dim3(cV / 64, (MC + 63) / 64), 256, 0, stream>>>(
      weighted, dec_W + (size_t)cE * cV, dec_b, nullptr, Cbig, MC, cV, cH);

  // 7) logZ, Pm, alpha
  k_logZ<<<dim3(cNP, cB), 256, 0, stream>>>(Abig, Cbig, logZ);
  k_pm<<<cNP, 64, 0, stream>>>(Abig, Cbig, logZ, trg, Pm);
  k_alpha<<<1, 64, 0, stream>>>(Pm, out);
}

// Round 2
// 1356.804 us; speedup vs baseline: 1.5353x; 1.5353x over previous
//
#include <hip/hip_runtime.h>
#include <hip/hip_bf16.h>
#include <math.h>

// Problem constants
static constexpr int cH = 512, cE = 512, cV = 32000;
static constexpr int K_SEG = 6, SOPI = 2, EOPI = 3;
static constexpr int cS = 40, cT = 40, cB = 16, cNP = 39;  // NP = T-1

typedef __attribute__((ext_vector_type(8))) short bf16x8;
typedef __attribute__((ext_vector_type(4))) float f32x4;

static __device__ __forceinline__ float bf2f(unsigned short u) {
  union { unsigned int i; float f; } c;
  c.i = (unsigned int)u << 16;
  return c.f;
}

// ---------------------------------------------------------------------------
// Transpose: out[c][r] = in[r][c]. R,C multiples of 64. outB (bf16) or outF.
__global__ __launch_bounds__(256) void k_transpose(
    const float* __restrict__ in, int R, int C,
    float* __restrict__ outF, __hip_bfloat16* __restrict__ outB) {
  __shared__ float tile[64][65];
  int tx = threadIdx.x & 63, ty = threadIdx.x >> 6;
  int r0 = blockIdx.y * 64, c0 = blockIdx.x * 64;
#pragma unroll
  for (int i = 0; i < 16; ++i) {
    int r = ty + i * 4;
    tile[r][tx] = in[(size_t)(r0 + r) * C + c0 + tx];
  }
  __syncthreads();
#pragma unroll
  for (int i = 0; i < 16; ++i) {
    int c = ty + i * 4;
    float v = tile[tx][c];
    if (outB) outB[(size_t)(c0 + c) * R + r0 + tx] = __float2bfloat16(v);
    else outF[(size_t)(c0 + c) * R + r0 + tx] = v;
  }
}

// ---------------------------------------------------------------------------
// Row gathers
__global__ void k_gather(const float* __restrict__ emb, const int* __restrict__ idx,
                         float* __restrict__ out, int R) {
  int r = blockIdx.x;
  if (r >= R) return;
  const float* s = emb + (size_t)idx[r] * cE;
  float* d = out + (size_t)r * cE;
  for (int e = threadIdx.x; e < cE; e += blockDim.x) d[e] = s[e];
}

__global__ void k_gather_bf16(const float* __restrict__ emb, const int* __restrict__ idx,
                              __hip_bfloat16* __restrict__ out, int R, int extraSOP) {
  int r = blockIdx.x;
  if (r >= R) return;
  int tok = (extraSOP && r == R - 1) ? SOPI : idx[r];
  const float* s = emb + (size_t)tok * cE;
  __hip_bfloat16* d = out + (size_t)r * cE;
  for (int e = threadIdx.x; e < cE; e += blockDim.x) d[e] = __float2bfloat16(s[e]);
}

// ---------------------------------------------------------------------------
// Generic f32 GEMM (small matmuls): C[M,N] = A[M,K] @ B[K,N] (+bias)
__global__ __launch_bounds__(256) void k_gemm(
    const float* __restrict__ A, const float* __restrict__ B,
    const float* __restrict__ bias, float* __restrict__ Cf, int M, int N, int K) {
  __shared__ float As[16][68];
  __shared__ float Bs[16][68];
  int tid = threadIdx.x;
  int m0 = blockIdx.y * 64, n0 = blockIdx.x * 64;
  int ty = tid >> 4, tx = tid & 15;
  float acc[4][4] = {};
  for (int k0 = 0; k0 < K; k0 += 16) {
    {
      int lk = tid & 15, lm = tid >> 4;
#pragma unroll
      for (int i = 0; i < 4; ++i) {
        int m = lm + i * 16;
        int gm = m0 + m;
        As[lk][m] = (gm < M) ? A[(size_t)gm * K + k0 + lk] : 0.f;
      }
      int ln = tid & 63, lk0 = tid >> 6;
#pragma unroll
      for (int i = 0; i < 4; ++i) {
        int k = lk0 + i * 4;
        Bs[k][ln] = B[(size_t)(k0 + k) * N + n0 + ln];
      }
    }
    __syncthreads();
#pragma unroll
    for (int kk = 0; kk < 16; ++kk) {
      float a[4], b[4];
#pragma unroll
      for (int i = 0; i < 4; ++i) a[i] = As[kk][ty * 4 + i];
#pragma unroll
      for (int j = 0; j < 4; ++j) b[j] = Bs[kk][tx * 4 + j];
#pragma unroll
      for (int i = 0; i < 4; ++i)
#pragma unroll
        for (int j = 0; j < 4; ++j) acc[i][j] += a[i] * b[j];
    }
    __syncthreads();
  }
#pragma unroll
  for (int i = 0; i < 4; ++i) {
    int gm = m0 + ty * 4 + i;
    if (gm >= M) continue;
#pragma unroll
    for (int j = 0; j < 4; ++j) {
      int gn = n0 + tx * 4 + j;
      float v = acc[i][j];
      if (bias) v += bias[gn];
      Cf[(size_t)gm * N + gn] = v;
    }
  }
}

// ---------------------------------------------------------------------------
// bf16 MFMA GEMM: C[M,N] = A[M,512] @ Wt^T  where Wt is [N][1024] bf16 (B^T),
// using k-range [koff, koff+512). Out bf16 (+f32 bias). N multiple of 128.
// Block 256 thr (4 waves as 2x2 of 64x64), BM=128, BN=128, BK=32.
__global__ __launch_bounds__(256) void k_gemm_mfma(
    const __hip_bfloat16* __restrict__ Ag, const __hip_bfloat16* __restrict__ Wt,
    const float* __restrict__ bias, __hip_bfloat16* __restrict__ Cb,
    int M, int N, int koff) {
  __shared__ unsigned short As[128 * 40];  // row stride 40 (80 B, 16B-aligned)
  __shared__ unsigned short Bs[128 * 40];
  const unsigned short* A = (const unsigned short*)Ag;
  const unsigned short* B = (const unsigned short*)Wt;
  int tid = threadIdx.x;
  int m0 = blockIdx.y * 128, n0 = blockIdx.x * 128;
  int w = tid >> 6, lane = tid & 63;
  int wr = w >> 1, wc = w & 1;
  int r16 = lane & 15, kg = lane >> 4;
  f32x4 acc[4][4] = {};
  for (int k0 = 0; k0 < 512; k0 += 32) {
    // stage A tile [128][32] and B tile [128][32]
#pragma unroll
    for (int pass = 0; pass < 2; ++pass) {
      int c = pass * 256 + tid;
      int row = c >> 2, kc = c & 3;
      uint4 av = {0u, 0u, 0u, 0u};
      int gm = m0 + row;
      if (gm < M) av = *(const uint4*)(A + (size_t)gm * 512 + k0 + kc * 8);
      *(uint4*)&As[row * 40 + kc * 8] = av;
      uint4 bv = *(const uint4*)(B + (size_t)(n0 + row) * 1024 + koff + k0 + kc * 8);
      *(uint4*)&Bs[row * 40 + kc * 8] = bv;
    }
    __syncthreads();
    bf16x8 a[4], b[4];
#pragma unroll
    for (int mi = 0; mi < 4; ++mi)
      a[mi] = *(const bf16x8*)&As[(wr * 64 + mi * 16 + r16) * 40 + kg * 8];
#pragma unroll
    for (int ni = 0; ni < 4; ++ni)
      b[ni] = *(const bf16x8*)&Bs[(wc * 64 + ni * 16 + r16) * 40 + kg * 8];
#pragma unroll
    for (int mi = 0; mi < 4; ++mi)
#pragma unroll
      for (int ni = 0; ni < 4; ++ni)
        acc[mi][ni] = __builtin_amdgcn_mfma_f32_16x16x32_bf16(a[mi], b[ni], acc[mi][ni], 0, 0, 0);
    __syncthreads();
  }
  // C/D layout: col = lane&15, row = (lane>>4)*4 + reg
#pragma unroll
  for (int mi = 0; mi < 4; ++mi) {
#pragma unroll
    for (int ni = 0; ni < 4; ++ni) {
      int gn = n0 + wc * 64 + ni * 16 + r16;
      float bv = bias ? bias[gn] : 0.f;
#pragma unroll
      for (int r = 0; r < 4; ++r) {
        int gm = m0 + wr * 64 + mi * 16 + kg * 4 + r;
        if (gm < M) Cb[(size_t)gm * N + gn] = __float2bfloat16(acc[mi][ni][r] + bv);
      }
    }
  }
}

// ---------------------------------------------------------------------------
// GRU step, u-sliced: grid (cH/16, 2). WhT is [1536][512] f32 (transposed Wh).
// Thread (b = tid&15, u16 = tid>>4). Weight reads broadcast across b-lanes.
__global__ __launch_bounds__(256) void k_gru_step2(
    const float* __restrict__ xp0, const float* __restrict__ WhT0, float* __restrict__ hs0,
    const float* __restrict__ xp1, const float* __restrict__ WhT1, float* __restrict__ hs1,
    int t) {
  const float* xp = blockIdx.y ? xp1 : xp0;
  const float* WhT = blockIdx.y ? WhT1 : WhT0;
  float* hs = blockIdx.y ? hs1 : hs0;
  __shared__ float hsh[16 * 516];  // [b][k], stride 516 (conflict-free float4)
  int tid = threadIdx.x;
  // stage previous h (16 x 512 f32)
  if (t == 0) {
#pragma unroll
    for (int i = 0; i < 8; ++i) {
      int lin = i * 1024 + tid * 4;
      int b = lin >> 9, k = lin & 511;
      *(f32x4*)&hsh[b * 516 + k] = f32x4{0.f, 0.f, 0.f, 0.f};
    }
  } else {
    const float* hp = hs + (size_t)(t - 1) * cB * cH;
#pragma unroll
    for (int i = 0; i < 8; ++i) {
      int lin = i * 1024 + tid * 4;
      int b = lin >> 9, k = lin & 511;
      *(f32x4*)&hsh[b * 516 + k] = *(const f32x4*)(hp + lin);
    }
  }
  __syncthreads();
  int b = tid & 15, u = blockIdx.x * 16 + (tid >> 4);
  const float* wr_p = WhT + (size_t)u * 512;
  const float* wz_p = WhT + (size_t)(512 + u) * 512;
  const float* wn_p = WhT + (size_t)(1024 + u) * 512;
  const float* hb = &hsh[b * 516];
  float hr = 0.f, hz = 0.f, hn = 0.f;
#pragma unroll 2
  for (int k = 0; k < 512; k += 4) {
    f32x4 hv = *(const f32x4*)(hb + k);
    f32x4 wr4 = *(const f32x4*)(wr_p + k);
    f32x4 wz4 = *(const f32x4*)(wz_p + k);
    f32x4 wn4 = *(const f32x4*)(wn_p + k);
#pragma unroll
    for (int c = 0; c < 4; ++c) {
      hr += hv[c] * wr4[c];
      hz += hv[c] * wz4[c];
      hn += hv[c] * wn4[c];
    }
  }
  size_t row3 = (size_t)(t * cB + b) * (3 * cH);
  float xr = xp[row3 + u], xz = xp[row3 + cH + u], xn = xp[row3 + 2 * cH + u];
  float r = 1.f / (1.f + __expf(-(xr + hr)));
  float z = 1.f / (1.f + __expf(-(xz + hz)));
  float n = tanhf(xn + r * hn);
  float h = (1.f - z) * n + z * hb[u];
  hs[(size_t)(t * cB + b) * cH + u] = h;
}

// ---------------------------------------------------------------------------
// energy[p,s,b] = sum_k v[k] * tanh(eproj[s,b,k] + qproj[p,b,k])  (fast tanh)
__global__ void k_energy(const float* __restrict__ eproj, const float* __restrict__ qproj,
                         const float* __restrict__ vv, float* __restrict__ energy) {
  int idx = blockIdx.x * blockDim.x + threadIdx.x;
  if (idx >= cNP * cS * cB) return;
  int b = idx & (cB - 1);
  int s = (idx >> 4) % cS;
  int p = idx / (cS * cB);
  const float* ep = eproj + (size_t)(s * cB + b) * cH;
  const float* qp = qproj + (size_t)(p * cB + b) * cH;
  float acc = 0.f;
  for (int k = 0; k < cH; k += 4) {
    f32x4 e4 = *(const f32x4*)(ep + k);
    f32x4 q4 = *(const f32x4*)(qp + k);
    f32x4 v4 = *(const f32x4*)(vv + k);
#pragma unroll
    for (int c = 0; c < 4; ++c) {
      float x = e4[c] + q4[c];
      float th = 1.f - 2.f / (1.f + __expf(2.f * x));
      acc += v4[c] * th;
    }
  }
  energy[idx] = acc;
}

// softmax over s. Block (p,b), 64 threads.
__global__ void k_softmax(float* __restrict__ energy) {
  int p = blockIdx.x, b = blockIdx.y;
  int s = threadIdx.x;
  float e = (s < cS) ? energy[(size_t)(p * cS + s) * cB + b] : -INFINITY;
  float m = e;
  for (int o = 32; o; o >>= 1) m = fmaxf(m, __shfl_down(m, o));
  m = __shfl(m, 0);
  float ex = (s < cS) ? __expf(e - m) : 0.f;
  float sum = ex;
  for (int o = 32; o; o >>= 1) sum += __shfl_down(sum, o);
  sum = __shfl(sum, 0);
  if (s < cS) energy[(size_t)(p * cS + s) * cB + b] = ex / sum;
}

// weighted[p,b,h] = sum_s attn[p,s,b] * enc_out[s,b,h]  -> bf16
__global__ void k_weighted(const float* __restrict__ attn, const float* __restrict__ enc_out,
                           __hip_bfloat16* __restrict__ weighted) {
  int h = blockIdx.x * 256 + threadIdx.x;
  int b = blockIdx.y, p = blockIdx.z;
  float acc = 0.f;
  for (int s = 0; s < cS; ++s)
    acc += attn[(size_t)(p * cS + s) * cB + b] * enc_out[(size_t)(s * cB + b) * cH + h];
  weighted[(size_t)(p * cB + b) * cH + h] = __float2bfloat16(acc);
}

// ---------------------------------------------------------------------------
// logZ[p,j,b] = log sum_v exp(A[row(p,j),v] + C[(p,b),v]); j=0 uses SOP row 640.
__global__ __launch_bounds__(256) void k_logZ(
    const __hip_bfloat16* __restrict__ Abig_, const __hip_bfloat16* __restrict__ Cbig_,
    float* __restrict__ logZ) {
  const unsigned short* Abig = (const unsigned short*)Abig_;
  const unsigned short* Cbig = (const unsigned short*)Cbig_;
  int p = blockIdx.x, b = blockIdx.y;
  int tid = threadIdx.x;
  float acc[7] = {};
  const unsigned short* crow = Cbig + (size_t)(p * cB + b) * cV;
  const unsigned short* arow[7];
  arow[0] = Abig + (size_t)(cT * cB) * cV;  // SOP row
#pragma unroll
  for (int j = 1; j <= 6; ++j) arow[j] = Abig + (size_t)(min(p + j, cT - 1) * cB + b) * cV;
  for (int v0 = tid * 8; v0 < cV; v0 += 2048) {
    uint4 cu = *(const uint4*)(crow + v0);
    const unsigned short* cs = (const unsigned short*)&cu;
    float cf[8];
#pragma unroll
    for (int e = 0; e < 8; ++e) cf[e] = bf2f(cs[e]);
#pragma unroll
    for (int j = 0; j < 7; ++j) {
      uint4 au = *(const uint4*)(arow[j] + v0);
      const unsigned short* as = (const unsigned short*)&au;
#pragma unroll
      for (int e = 0; e < 8; ++e) acc[j] += __expf(bf2f(as[e]) + cf[e]);
    }
  }
  __shared__ float red[256];
#pragma unroll
  for (int j = 0; j < 7; ++j) {
    red[tid] = acc[j];
    __syncthreads();
    for (int st = 128; st; st >>= 1) {
      if (tid < st) red[tid] += red[tid + st];
      __syncthreads();
    }
    if (tid == 0) logZ[(size_t)(p * 7 + j) * cB + b] = logf(red[0]);
    __syncthreads();
  }
}

// Pm[p,j,b] = cumsum_j chain_lp + eop_lp
__global__ void k_pm(const __hip_bfloat16* __restrict__ Abig, const __hip_bfloat16* __restrict__ Cbig,
                     const float* __restrict__ logZ, const int* __restrict__ trg,
                     float* __restrict__ Pm) {
  int p = blockIdx.x;
  int b = threadIdx.x;
  if (b >= cB) return;
  const __hip_bfloat16* crow = Cbig + (size_t)(p * cB + b) * cV;
  float cEop = __bfloat162float(crow[EOPI]);
  float cum = 0.f;
  for (int j = 0; j < K_SEG; ++j) {
    int arow = (j == 0) ? (cT * cB) : (min(p + j, cT - 1) * cB + b);
    int tok = trg[min(p + 1 + j, cT - 1) * cB + b];
    float chain = __bfloat162float(Abig[(size_t)arow * cV + tok]) +
                  __bfloat162float(crow[tok]) - logZ[(size_t)(p * 7 + j) * cB + b];
    cum += chain;
    int erow = min(p + j + 1, cT - 1) * cB + b;
    float eop = __bfloat162float(Abig[(size_t)erow * cV + EOPI]) + cEop -
                logZ[(size_t)(p * 7 + j + 1) * cB + b];
    Pm[(size_t)(p * K_SEG + j) * cB + b] = cum + eop;
  }
}

// Final alpha recursion
__global__ void k_alpha(const float* __restrict__ Pm, float* __restrict__ out) {
  __shared__ float al[cB][cT];
  int b = threadIdx.x;
  if (b >= cB) return;
  al[b][0] = 0.f;
  for (int e = 1; e < cT; ++e) {
    float vals[K_SEG];
    float m = -INFINITY;
#pragma unroll
    for (int d = 0; d < K_SEG; ++d) {
      int p = e - 1 - d;
      float v = (p >= 0) ? al[b][p] + Pm[(size_t)(p * K_SEG + d) * cB + b] : -INFINITY;
      vals[d] = v;
      m = fmaxf(m, v);
    }
    float s = 0.f;
#pragma unroll
    for (int d = 0; d < K_SEG; ++d) s += __expf(vals[d] - m);
    al[b][e] = m + logf(s);
  }
  out[b] = al[b][cT - 1];
}

// ---------------------------------------------------------------------------
extern "C" void kernel_launch(void* const* d_in, const int* in_sizes, int n_in,
                              void* d_out, int out_size, void* d_ws, size_t ws_size,
                              hipStream_t stream) {
  const int* src = (const int*)d_in[0];
  const int* trg = (const int*)d_in[1];
  const float* emb_src = (const float*)d_in[2];
  const float* emb_trg = (const float*)d_in[3];
  const float* enc_Wx = (const float*)d_in[4];
  const float* enc_Wh = (const float*)d_in[5];
  const float* enc_b = (const float*)d_in[6];
  const float* tgt_Wx = (const float*)d_in[7];
  const float* tgt_Wh = (const float*)d_in[8];
  const float* tgt_b = (const float*)d_in[9];
  const float* attn_We = (const float*)d_in[10];
  const float* attn_Wq = (const float*)d_in[11];
  const float* attn_v = (const float*)d_in[12];
  const float* dec_W = (const float*)d_in[13];
  const float* dec_b = (const float*)d_in[14];
  float* out = (float*)d_out;

  char* ws = (char*)d_ws;
  size_t off = 0;
  auto alloc = [&](size_t bytes) -> void* {
    size_t o = (off + 255) & ~(size_t)255;
    off = o + bytes;
    return (void*)(ws + o);
  };
  float* xe_src = (float*)alloc((size_t)cS * cB * cE * 4);
  float* xe_tgt = (float*)alloc((size_t)cT * cB * cE * 4);
  float* xp_src = (float*)alloc((size_t)cS * cB * 3 * cH * 4);
  float* xp_tgt = (float*)alloc((size_t)cT * cB * 3 * cH * 4);
  float* hs_enc = (float*)alloc((size_t)cS * cB * cH * 4);
  float* hs_tgt = (float*)alloc((size_t)cT * cB * cH * 4);
  float* WhT0 = (float*)alloc((size_t)3 * cH * cH * 4);
  float* WhT1 = (float*)alloc((size_t)3 * cH * cH * 4);
  float* eproj = (float*)alloc((size_t)cS * cB * cH * 4);
  float* qproj = (float*)alloc((size_t)cNP * cB * cH * 4);
  float* energy = (float*)alloc((size_t)cNP * cS * cB * 4);
  __hip_bfloat16* Wb = (__hip_bfloat16*)alloc((size_t)cNP * cB * cH * 2);
  __hip_bfloat16* XAb = (__hip_bfloat16*)alloc((size_t)(cT * cB + 1) * cE * 2);
  __hip_bfloat16* Wt = (__hip_bfloat16*)alloc((size_t)cV * (cE + cH) * 2);
  __hip_bfloat16* Abig = (__hip_bfloat16*)alloc((size_t)(cT * cB + 1) * cV * 2);
  __hip_bfloat16* Cbig = (__hip_bfloat16*)alloc((size_t)cNP * cB * cV * 2);
  float* logZ = (float*)alloc((size_t)cNP * 7 * cB * 4);
  float* Pm = (float*)alloc((size_t)cNP * K_SEG * cB * 4);
  if (off > ws_size) return;

  const int MA = cT * cB + 1;  // 641
  const int MC = cNP * cB;     // 624

  // 0) weight transposes: Wt = dec_W^T (bf16), WhT = Wh^T (f32)
  k_transpose<<<dim3(cV / 64, (cE + cH) / 64), 256, 0, stream>>>(dec_W, cE + cH, cV, nullptr, Wt);
  k_transpose<<<dim3(3 * cH / 64, cH / 64), 256, 0, stream>>>(enc_Wh, cH, 3 * cH, WhT0, nullptr);
  k_transpose<<<dim3(3 * cH / 64, cH / 64), 256, 0, stream>>>(tgt_Wh, cH, 3 * cH, WhT1, nullptr);

  // 1) embedding gathers
  k_gather<<<cS * cB, 256, 0, stream>>>(emb_src, src, xe_src, cS * cB);
  k_gather<<<cT * cB, 256, 0, stream>>>(emb_trg, trg, xe_tgt, cT * cB);
  k_gather_bf16<<<MA, 256, 0, stream>>>(emb_trg, trg, XAb, MA, 1);

  // 2) xp = xe @ Wx + b
  k_gemm<<<dim3(3 * cH / 64, (cS * cB + 63) / 64), 256, 0, stream>>>(
      xe_src, enc_Wx, enc_b, xp_src, cS * cB, 3 * cH, cE);
  k_gemm<<<dim3(3 * cH / 64, (cT * cB + 63) / 64), 256, 0, stream>>>(
      xe_tgt, tgt_Wx, tgt_b, xp_tgt, cT * cB, 3 * cH, cE);

  // 3) GRU scans (u-sliced, transposed weights)
  for (int t = 0; t < cT; ++t)
    k_gru_step2<<<dim3(cH / 16, 2), 256, 0, stream>>>(
        xp_src, WhT0, hs_enc, xp_tgt, WhT1, hs_tgt, t);

  // 4) attention projections
  k_gemm<<<dim3(cH / 64, (cS * cB + 63) / 64), 256, 0, stream>>>(
      hs_enc, attn_We, nullptr, eproj, cS * cB, cH, cH);
  k_gemm<<<dim3(cH / 64, (MC + 63) / 64), 256, 0, stream>>>(
      hs_tgt, attn_Wq, nullptr, qproj, MC, cH, cH);

  // 5) energy / softmax / weighted context
  k_energy<<<(cNP * cS * cB + 255) / 256, 256, 0, stream>>>(eproj, qproj, attn_v, energy);
  k_softmax<<<dim3(cNP, cB), 64, 0, stream>>>(energy);
  k_weighted<<<dim3(cH / 256, cB, cNP), 256, 0, stream>>>(energy, hs_enc, Wb);

  // 6) decoder GEMMs via MFMA -> bf16 Abig / Cbig
  k_gemm_mfma<<<dim3(cV / 128, (MA + 127) / 128), 256, 0, stream>>>(
      XAb, Wt, nullptr, Abig, MA, cV, 0);
  k_gemm_mfma<<<dim3(cV / 128, (MC + 127) / 128), 256, 0, stream>>>(
      Wb, Wt, dec_b, Cbig, MC, cV, cE);

  // 7) logZ, Pm, alpha
  k_logZ<<<dim3(cNP, cB), 256, 0, stream>>>(Abig, Cbig, logZ);
  k_pm<<<cNP, 64, 0, stream>>>(Abig, Cbig, logZ, trg, Pm);
  k_alpha<<<1, 64, 0, stream>>>(Pm, out);
}